// Round 3
// baseline (196.644 us; speedup 1.0000x reference)
//
#include <hip/hip_runtime.h>
#include <cstdint>

#define BB 16
#define LL 32768
#define NC 512               // chunks per (b,dir)
#define NSPAN 32             // NC/16 spans per (b,dir)
#define SPLEN 16             // chunks per span

// ---- weight block layout (floats) in ws[0..4096B) ----
#define WD_SZ 256            // per-direction block
#define XPW 0                // x_proj rows [33][4]
#define CVW 132              // conv_w [4][4]
#define CVB 148              // conv_b [4]
#define DTW 152              // dt_proj_w [4]
#define DTB 156              // dt_proj_b [4]
#define AW  160              // A = -exp(A_log)*log2(e) [4][16]  (pre-scaled for exp2)
#define DW  224              // D [4]
#define G_INPROJ 512         // in_proj [8][2]
#define G_NORMW 528
#define G_OUTP 530           // out_proj [2][4]
#define G_NORMF 538
#define FLG 1000             // 1.0f if inputs/outputs fp32, 0.0f if bf16

// ---- ws byte offsets (~145 MiB) ----
#define PQ_OFF 4096
#define PQ_BYTES ((size_t)BB*2*NC*64*8)            // 8.39 MB  per-chunk (P,Q)
#define SP_OFF (PQ_OFF + PQ_BYTES)
#define SP_BYTES ((size_t)BB*2*NSPAN*64*8)         // 0.52 MB  span tables
#define WG_OFF (SP_OFF + SP_BYTES)
#define WG_BYTES ((size_t)BB*NC*2*64*64*2)         // 134.2 MB W = bf16(P*C), [g][dir][t][dn]
#define YB_OFF (WG_OFF + WG_BYTES)
#define YB_BYTES ((size_t)BB*NC*64*4*4)            // 8.39 MB  ybase fp32 [g][t][d]

#define LOG2E 1.4426950408889634f

__device__ __forceinline__ float bf2f(unsigned short u){ return __uint_as_float(((unsigned int)u)<<16); }
__device__ __forceinline__ float blo(unsigned int u){ return __uint_as_float(u<<16); }
__device__ __forceinline__ float bhi(unsigned int u){ return __uint_as_float(u & 0xffff0000u); }

// HW packed f32->bf16 (RNE). 1 VALU inst.
__device__ __forceinline__ unsigned int cvtpk(float lo, float hi){
  unsigned int r;
  asm("v_cvt_pk_bf16_f32 %0, %1, %2" : "=v"(r) : "v"(lo), "v"(hi));
  return r;
}
__device__ __forceinline__ unsigned short cvt1(float x){
  return (unsigned short)cvtpk(x, x);
}

__device__ __forceinline__ float siluf(float x){ return x / (1.f + __expf(-x)); }
__device__ __forceinline__ float softplusf_(float x){ return fmaxf(x,0.f) + log1pf(__expf(-fabsf(x))); }

// raw v_exp_f32 (exp2). A is pre-scaled by log2(e) so no extra mul.
__device__ __forceinline__ float exp2fast(float x){
#if __has_builtin(__builtin_amdgcn_exp2f)
  return __builtin_amdgcn_exp2f(x);
#else
  float r; asm("v_exp_f32 %0, %1\ns_nop 0" : "=v"(r) : "v"(x)); return r;
#endif
}

// sum over the 16-lane DPP row (lanes n=0..15 of each d-group).
__device__ __forceinline__ float rowsum16(float x){
  asm("s_nop 1\n\t"
      "v_add_f32_dpp %0, %0, %0 row_ror:1 row_mask:0xf bank_mask:0xf\n\t"
      "s_nop 1\n\t"
      "v_add_f32_dpp %0, %0, %0 row_ror:2 row_mask:0xf bank_mask:0xf\n\t"
      "s_nop 1\n\t"
      "v_add_f32_dpp %0, %0, %0 row_ror:4 row_mask:0xf bank_mask:0xf\n\t"
      "s_nop 1\n\t"
      "v_add_f32_dpp %0, %0, %0 row_ror:8 row_mask:0xf bank_mask:0xf"
      : "+v"(x));
  return x;
}

__device__ __forceinline__ float ldw(const void* p, int i, int isf){
  return isf ? ((const float*)p)[i] : bf2f(((const unsigned short*)p)[i]);
}
__device__ __forceinline__ float2 hid2(const void* hid, int isf, int b, int t){
  if (isf){
    const float* p = (const float*)hid;
    return make_float2(p[(size_t)b*2*LL + t], p[(size_t)b*2*LL + LL + t]);
  }
  const unsigned short* p = (const unsigned short*)hid;
  return make_float2(bf2f(p[(size_t)b*2*LL + t]), bf2f(p[(size_t)b*2*LL + LL + t]));
}
__device__ __forceinline__ float4 xrow(const void* __restrict__ hid, int isf,
                                       const float* __restrict__ W, int b, int t){
  float2 h = hid2(hid, isf, b, t);
  float ms = rsqrtf(0.5f*(h.x*h.x + h.y*h.y) + 1e-5f);
  float v0 = h.x*ms*W[G_NORMW], v1 = h.y*ms*W[G_NORMW+1];
  float4 x;
  x.x = W[G_INPROJ+0]*v0 + W[G_INPROJ+1]*v1;
  x.y = W[G_INPROJ+2]*v0 + W[G_INPROJ+3]*v1;
  x.z = W[G_INPROJ+4]*v0 + W[G_INPROJ+5]*v1;
  x.w = W[G_INPROJ+6]*v0 + W[G_INPROJ+7]*v1;
  return x;
}

// ---------------- kernel 0: weight prep ----------------
__global__ void k_prep(const void* __restrict__ normw, const void* __restrict__ inpj,
    const void* __restrict__ cwf, const void* __restrict__ cbf,
    const void* __restrict__ xpf, const void* __restrict__ dwf,
    const void* __restrict__ dbf, const void* __restrict__ alf,
    const void* __restrict__ ddf,
    const void* __restrict__ cwb, const void* __restrict__ cbb,
    const void* __restrict__ xpb, const void* __restrict__ dwb,
    const void* __restrict__ dbb, const void* __restrict__ alb,
    const void* __restrict__ ddb,
    const void* __restrict__ outp, const void* __restrict__ nfw,
    float* __restrict__ W)
{
  const int isf = (((const unsigned int*)ddf)[0] == 0x3F800000u) ? 1 : 0;
  int t = threadIdx.x;
  for (int i=t;i<132;i+=256){ W[XPW+i]=ldw(xpf,i,isf); W[WD_SZ+XPW+i]=ldw(xpb,i,isf); }
  for (int i=t;i<16;i+=256){ W[CVW+i]=ldw(cwf,i,isf); W[WD_SZ+CVW+i]=ldw(cwb,i,isf); W[G_INPROJ+i]=ldw(inpj,i,isf); }
  for (int i=t;i<4;i+=256){
    W[CVB+i]=ldw(cbf,i,isf); W[WD_SZ+CVB+i]=ldw(cbb,i,isf);
    W[DTW+i]=ldw(dwf,i,isf); W[WD_SZ+DTW+i]=ldw(dwb,i,isf);
    W[DTB+i]=ldw(dbf,i,isf); W[WD_SZ+DTB+i]=ldw(dbb,i,isf);
    W[DW+i] =ldw(ddf,i,isf); W[WD_SZ+DW+i] =ldw(ddb,i,isf);
  }
  for (int i=t;i<64;i+=256){
    W[AW+i]       = -__expf(ldw(alf,i,isf)) * LOG2E;
    W[WD_SZ+AW+i] = -__expf(ldw(alb,i,isf)) * LOG2E;
  }
  for (int i=t;i<8;i+=256) W[G_OUTP+i]=ldw(outp,i,isf);
  for (int i=t;i<2;i+=256){ W[G_NORMW+i]=ldw(normw,i,isf); W[G_NORMF+i]=ldw(nfw,i,isf); }
  if (t==0) W[FLG] = (float)isf;
}

// ---- per-direction local scan: produces (P,Q), y_loc rowsums, and W=bf16(P*C).
// DR template keeps indices compile-time. All lanes execute (DPP needs full wave).
template<int DR>
__device__ __forceinline__ float2 scan_store(const float (* __restrict__ dtPd)[68],
    const unsigned short (* __restrict__ dtud)[68],
    const unsigned int (* __restrict__ bcd)[68],
    float (* __restrict__ ySd)[68],
    unsigned short* __restrict__ wrow,   // global: [t][dn], this dir's base
    float Ax, int d, int n, int dn)
{
  unsigned short* wr   = wrow + dn;          // one-time lane offset
  unsigned short* wrHi = wr + 32*64;         // split base so imm offset < 4096B
  float P = 1.f, h = 0.f;
  for (int j4=0; j4<16; j4++){
    const int t0 = DR ? 60-4*j4 : 4*j4;
    float4  d4 = *(const float4*)&dtPd[d][t0];
    ushort4 u4 = *(const ushort4*)&dtud[d][t0];
    uint4   c4 = *(const uint4*)&bcd[n][t0];
    float da[4]={d4.x,d4.y,d4.z,d4.w};
    unsigned short ua[4]={u4.x,u4.y,u4.z,u4.w};
    unsigned int ca[4]={c4.x,c4.y,c4.z,c4.w};
    float s[4];
    #pragma unroll
    for (int jr=0; jr<4; jr++){
      const int k  = DR ? 3-jr : jr;         // bwd consumes t descending
      const int tt = t0 + k;
      float e = exp2fast(Ax*da[k]);
      P *= e;
      float Cf = bhi(ca[k]);
      h = fmaf(e, h, bf2f(ua[k])*blo(ca[k]));
      ((tt < 32) ? wr : wrHi)[(tt & 31)*64] = cvt1(P*Cf);  // coalesced 128B/t
      s[k] = rowsum16(h*Cf);
    }
    if (n == 0) *(float4*)&ySd[d][t0] = make_float4(s[0],s[1],s[2],s[3]);
  }
  return make_float2(P, h);
}

// ---------------- kernel 1: per-chunk local scan, dir per wave ----------------
__global__ __launch_bounds__(128, 4) void k_chunk2(const void* __restrict__ hid,
    const float* __restrict__ W, float2* __restrict__ PQ,
    unsigned short* __restrict__ Wg, float4* __restrict__ YB)
{
  // xb (1120B, dead after preamble) overlaps yS (2176B, written during scan)
  __shared__ __align__(16) char smx[2176];
  __shared__ __align__(16) float dtP[2][4][68];            // 2176
  __shared__ __align__(16) unsigned short dtuP[2][4][68];  // 1088
  __shared__ __align__(16) unsigned int BCp[2][16][68];    // 8704 (B | C<<16) bf16
  __shared__ __align__(16) float uD[2][256];               // 2048 u*D
  float4* xb = (float4*)smx;
  float (*yS)[4][68] = (float (*)[4][68])smx;

  const int tid  = threadIdx.x;
  const int wid  = tid >> 6;         // 0=fwd wave, 1=bwd wave
  const int lane = tid & 63;
  const int gid  = blockIdx.x;       // (b,c)
  const int c    = gid & (NC-1);
  const int b    = gid >> 9;
  const int isf  = (int)W[FLG];

  if (wid == 0){
    int t = c*64 + lane;
    xb[lane+3] = xrow(hid, isf, W, b, t);
    if (lane < 3){
      int t2 = c*64 - 3 + lane;
      float4 v = make_float4(0.f,0.f,0.f,0.f);
      if (t2 >= 0) v = xrow(hid, isf, W, b, t2);
      xb[lane] = v;
    }
    if (lane >= 61){
      int t3 = c*64 + lane + 3;
      float4 v = make_float4(0.f,0.f,0.f,0.f);
      if (t3 < LL) v = xrow(hid, isf, W, b, t3);
      xb[lane+6] = v;
    }
  }
  __syncthreads();
  {
    const float* Wd = W + wid*WD_SZ;
    float4 a0,a1,a2,a3;
    if (wid == 0){ a0=xb[lane];   a1=xb[lane+1]; a2=xb[lane+2]; a3=xb[lane+3]; }
    else         { a0=xb[lane+6]; a1=xb[lane+5]; a2=xb[lane+4]; a3=xb[lane+3]; }
    float u[4];
    u[0] = siluf(Wd[CVB+0] + Wd[CVW+ 0]*a0.x + Wd[CVW+ 1]*a1.x + Wd[CVW+ 2]*a2.x + Wd[CVW+ 3]*a3.x);
    u[1] = siluf(Wd[CVB+1] + Wd[CVW+ 4]*a0.y + Wd[CVW+ 5]*a1.y + Wd[CVW+ 6]*a2.y + Wd[CVW+ 7]*a3.y);
    u[2] = siluf(Wd[CVB+2] + Wd[CVW+ 8]*a0.z + Wd[CVW+ 9]*a1.z + Wd[CVW+10]*a2.z + Wd[CVW+11]*a3.z);
    u[3] = siluf(Wd[CVB+3] + Wd[CVW+12]*a0.w + Wd[CVW+13]*a1.w + Wd[CVW+14]*a2.w + Wd[CVW+15]*a3.w);
    float dtr = Wd[XPW+0]*u[0] + Wd[XPW+1]*u[1] + Wd[XPW+2]*u[2] + Wd[XPW+3]*u[3];
    float4 ud4;
    #pragma unroll
    for (int d2=0; d2<4; d2++){
      float dt = softplusf_(fmaf(Wd[DTW+d2], dtr, Wd[DTB+d2]));
      dtP[wid][d2][lane]  = dt;
      dtuP[wid][d2][lane] = cvt1(dt*u[d2]);
      ((float*)&ud4)[d2] = u[d2]*Wd[DW+d2];
    }
    *(float4*)&uD[wid][lane*4] = ud4;
    #pragma unroll
    for (int n=0; n<16; n++){
      float Bn = Wd[XPW+(1+n)*4+0]*u[0] + Wd[XPW+(1+n)*4+1]*u[1]
               + Wd[XPW+(1+n)*4+2]*u[2] + Wd[XPW+(1+n)*4+3]*u[3];
      float Cn = Wd[XPW+(17+n)*4+0]*u[0] + Wd[XPW+(17+n)*4+1]*u[1]
               + Wd[XPW+(17+n)*4+2]*u[2] + Wd[XPW+(17+n)*4+3]*u[3];
      BCp[wid][n][lane] = cvtpk(Bn, Cn);
    }
  }
  __syncthreads();   // also protects xb->yS union

  const int d = lane>>4, n = lane&15;
  const float Ax = W[wid*WD_SZ + AW + d*16 + n];
  unsigned short* wrow = Wg + ((size_t)gid*2 + wid)*64*64;
  float2 pq;
  size_t idx;
  if (wid == 0){
    pq  = scan_store<0>(dtP[0], dtuP[0], BCp[0], yS[0], wrow, Ax, d, n, lane);
    idx = ((size_t)(b*2+0)*NC + c);
  } else {
    pq  = scan_store<1>(dtP[1], dtuP[1], BCp[1], yS[1], wrow, Ax, d, n, lane);
    idx = ((size_t)(b*2+1)*NC + (NC-1-c));
  }
  PQ[idx*64 + lane] = pq;
  __syncthreads();

  // ybase = y_loc_f + y_loc_b + uD_f + uD_b   (fp32, [t][d] float4)
  if (wid == 0){
    float4 v;
    v.x = yS[0][0][lane] + yS[1][0][lane] + uD[0][lane*4+0] + uD[1][lane*4+0];
    v.y = yS[0][1][lane] + yS[1][1][lane] + uD[0][lane*4+1] + uD[1][lane*4+1];
    v.z = yS[0][2][lane] + yS[1][2][lane] + uD[0][lane*4+2] + uD[1][lane*4+2];
    v.w = yS[0][3][lane] + yS[1][3][lane] + uD[0][lane*4+3] + uD[1][lane*4+3];
    YB[(size_t)gid*64 + lane] = v;
  }
}

// ---------------- kernel 2: span tables (16-chunk composition) ----------------
__global__ __launch_bounds__(64) void k_spans(const float2* __restrict__ PQ,
                                              float2* __restrict__ SP)
{
  const int blk  = blockIdx.x;           // bd*NSPAN + span
  const int lane = threadIdx.x;
  const int bd   = blk >> 5, span = blk & (NSPAN-1);
  const float2* p = PQ + ((size_t)bd*NC + span*SPLEN)*64 + lane;
  float2 v[SPLEN];
  #pragma unroll
  for (int k=0;k<SPLEN;k++) v[k] = p[k*64];
  float A = 1.f, Bc = 0.f;
  #pragma unroll
  for (int k=0;k<SPLEN;k++){ A *= v[k].x; Bc = fmaf(v[k].x, Bc, v[k].y); }
  SP[((size_t)bd*NSPAN + span)*64 + lane] = make_float2(A,Bc);
}

// 16-term bf16 dot against wave-uniform h0 slice (LDS broadcast reads)
__device__ __forceinline__ float dot16(uint4 q0, uint4 q1, const float* h){
  float4 h0 = *(const float4*)(h+0),  h1 = *(const float4*)(h+4);
  float4 h2 = *(const float4*)(h+8),  h3 = *(const float4*)(h+12);
  float cacc = 0.f;
  cacc = fmaf(blo(q0.x), h0.x, cacc); cacc = fmaf(bhi(q0.x), h0.y, cacc);
  cacc = fmaf(blo(q0.y), h0.z, cacc); cacc = fmaf(bhi(q0.y), h0.w, cacc);
  cacc = fmaf(blo(q0.z), h1.x, cacc); cacc = fmaf(bhi(q0.z), h1.y, cacc);
  cacc = fmaf(blo(q0.w), h1.z, cacc); cacc = fmaf(bhi(q0.w), h1.w, cacc);
  cacc = fmaf(blo(q1.x), h2.x, cacc); cacc = fmaf(bhi(q1.x), h2.y, cacc);
  cacc = fmaf(blo(q1.y), h2.z, cacc); cacc = fmaf(bhi(q1.y), h2.w, cacc);
  cacc = fmaf(blo(q1.z), h3.x, cacc); cacc = fmaf(bhi(q1.z), h3.y, cacc);
  cacc = fmaf(blo(q1.w), h3.z, cacc); cacc = fmaf(bhi(q1.w), h3.w, cacc);
  return cacc;
}

// ---------------- kernel 3: compose h0 + apply W·h0 + combine + out ----------------
__global__ __launch_bounds__(64) void k_final(const void* __restrict__ hid,
    const float* __restrict__ W, const float2* __restrict__ PQ,
    const float2* __restrict__ SP, const unsigned short* __restrict__ Wg,
    const float4* __restrict__ YB, void* __restrict__ out)
{
  __shared__ float h0s[2][64];
  const int lane = threadIdx.x;
  const int gid  = blockIdx.x;       // (b,c)
  const int c    = gid & (NC-1);
  const int b    = gid >> 9;
  const int isf  = (int)W[FLG];

  // ---- phase 1 (lane = (d,n)): compose entry state for both dirs
  #pragma unroll
  for (int dir=0; dir<2; dir++){
    const int p  = dir ? (NC-1-c) : c;      // position in this dir's chunk sequence
    const int bd = b*2 + dir;
    const int s  = p >> 4, wn = p & 15;
    const float2* SPb = SP + (size_t)bd*NSPAN*64 + lane;
    const float2* PQb = PQ + ((size_t)bd*NC + (p & ~15))*64 + lane;
    float h = 0.f;
    #pragma unroll
    for (int jg=0; jg<4; jg++){
      if (jg*8 < s){                         // wave-uniform group skip
        float2 v[8];
        #pragma unroll
        for (int j=0;j<8;j++){ int jj = jg*8+j; v[j] = SPb[(size_t)(jj<s?jj:0)*64]; }
        #pragma unroll
        for (int j=0;j<8;j++){ int jj = jg*8+j; if (jj<s) h = fmaf(v[j].x, h, v[j].y); }
      }
    }
    #pragma unroll
    for (int jg=0; jg<2; jg++){
      if (jg*8 < wn){
        float2 v[8];
        #pragma unroll
        for (int j=0;j<8;j++){ int jj = jg*8+j; v[j] = PQb[(size_t)(jj<wn?jj:0)*64]; }
        #pragma unroll
        for (int j=0;j<8;j++){ int jj = jg*8+j; if (jj<wn) h = fmaf(v[j].x, h, v[j].y); }
      }
    }
    h0s[dir][lane] = h;
  }
  __syncthreads();

  // ---- phase 2 (lane = t): corrections + combine + out_proj + rmsnorm
  {
    const int t = lane;
    const uint4* wrF = (const uint4*)(Wg + (((size_t)gid*2 + 0)*64 + t)*64);
    const uint4* wrB = (const uint4*)(Wg + (((size_t)gid*2 + 1)*64 + t)*64);
    uint4 wf[8], wb[8];
    #pragma unroll
    for (int q=0;q<8;q++) wf[q] = wrF[q];
    #pragma unroll
    for (int q=0;q<8;q++) wb[q] = wrB[q];
    float4 yb = YB[(size_t)gid*64 + t];

    float corr[4];
    #pragma unroll
    for (int d2=0; d2<4; d2++){
      float cf = dot16(wf[d2*2], wf[d2*2+1], &h0s[0][d2*16]);
      float cb = dot16(wb[d2*2], wb[d2*2+1], &h0s[1][d2*16]);
      corr[d2] = cf + cb;
    }

    const int tg = c*64 + t;
    float2 r = hid2(hid, isf, b, tg);
    float ms0 = rsqrtf(0.5f*(r.x*r.x + r.y*r.y) + 1e-5f);
    float v0 = r.x*ms0*W[G_NORMW], v1 = r.y*ms0*W[G_NORMW+1];
    float z0 = siluf(W[G_INPROJ+ 8]*v0 + W[G_INPROJ+ 9]*v1);
    float z1 = siluf(W[G_INPROJ+10]*v0 + W[G_INPROJ+11]*v1);
    float z2 = siluf(W[G_INPROJ+12]*v0 + W[G_INPROJ+13]*v1);
    float z3 = siluf(W[G_INPROJ+14]*v0 + W[G_INPROJ+15]*v1);

    float y0 = (yb.x + corr[0]) * z0;
    float y1 = (yb.y + corr[1]) * z1;
    float y2 = (yb.z + corr[2]) * z2;
    float y3 = (yb.w + corr[3]) * z3;
    float o0 = W[G_OUTP+0]*y0 + W[G_OUTP+1]*y1 + W[G_OUTP+2]*y2 + W[G_OUTP+3]*y3;
    float o1 = W[G_OUTP+4]*y0 + W[G_OUTP+5]*y1 + W[G_OUTP+6]*y2 + W[G_OUTP+7]*y3;
    o0 += r.x;
    o1 += r.y;
    float ms = rsqrtf(0.5f*(o0*o0 + o1*o1) + 1e-5f);
    float e0 = o0*ms*W[G_NORMF], e1 = o1*ms*W[G_NORMF+1];
    size_t i0 = (size_t)b*2*LL + tg, i1 = i0 + LL;
    if (isf){
      ((float*)out)[i0] = e0;
      ((float*)out)[i1] = e1;
    } else {
      ((unsigned short*)out)[i0] = cvt1(e0);
      ((unsigned short*)out)[i1] = cvt1(e1);
    }
  }
}

extern "C" void kernel_launch(void* const* d_in, const int* in_sizes, int n_in,
                              void* d_out, int out_size, void* d_ws, size_t ws_size,
                              hipStream_t stream)
{
  (void)in_sizes; (void)n_in; (void)out_size; (void)ws_size;
  const void* hid   = d_in[0];
  const void* normw = d_in[1];
  const void* inpj  = d_in[2];
  const void* cwf   = d_in[3];
  const void* cbf   = d_in[4];
  const void* xpf   = d_in[5];
  const void* dwf   = d_in[6];
  const void* dbf   = d_in[7];
  const void* alf   = d_in[8];
  const void* ddf   = d_in[9];
  const void* cwb   = d_in[10];
  const void* cbb   = d_in[11];
  const void* xpb   = d_in[12];
  const void* dwb   = d_in[13];
  const void* dbb   = d_in[14];
  const void* alb   = d_in[15];
  const void* ddb   = d_in[16];
  const void* outp  = d_in[17];
  const void* nfw   = d_in[18];

  float* W            = (float*)d_ws;
  float2* PQ          = (float2*)((char*)d_ws + PQ_OFF);
  float2* SPt         = (float2*)((char*)d_ws + SP_OFF);
  unsigned short* Wg  = (unsigned short*)((char*)d_ws + WG_OFF);
  float4* YB          = (float4*)((char*)d_ws + YB_OFF);

  k_prep<<<1,256,0,stream>>>(normw, inpj, cwf, cbf, xpf, dwf, dbf, alf, ddf,
                             cwb, cbb, xpb, dwb, dbb, alb, ddb, outp, nfw, W);
  k_chunk2<<<BB*NC, 128, 0, stream>>>(hid, W, PQ, Wg, YB);
  k_spans<<<BB*2*NSPAN, 64, 0, stream>>>(PQ, SPt);
  k_final<<<BB*NC, 64, 0, stream>>>(hid, W, PQ, SPt, Wg, YB, d_out);
}

// Round 4
// 191.503 us; speedup vs baseline: 1.0268x; 1.0268x over previous
//
#include <hip/hip_runtime.h>
#include <cstdint>

#define BB 16
#define LL 32768
#define NC 512               // chunks per (b,dir)
#define NSPAN 32             // NC/16 spans per (b,dir)
#define SPLEN 16             // chunks per span

// ---- weight block layout (floats) in ws[0..4096B) ----
#define WD_SZ 256            // per-direction block
#define XPW 0                // x_proj rows [33][4]
#define CVW 132              // conv_w [4][4]
#define CVB 148              // conv_b [4]
#define DTW 152              // dt_proj_w [4]
#define DTB 156              // dt_proj_b [4]
#define AW  160              // A = -exp(A_log)*log2(e) [4][16]  (pre-scaled for exp2)
#define DW  224              // D [4]
#define G_INPROJ 512         // in_proj [8][2]
#define G_NORMW 528
#define G_OUTP 530           // out_proj [2][4]
#define G_NORMF 538
#define FLG 1000             // 1.0f if inputs/outputs fp32, 0.0f if bf16

// ---- ws byte offsets (~152 MiB) ----
#define PQ_OFF 4096
#define PQ_BYTES ((size_t)BB*2*NC*64*8)            // 8.39 MB  per-chunk (P,Q)
#define SP_OFF (PQ_OFF + PQ_BYTES)
#define SP_BYTES ((size_t)BB*2*NSPAN*64*8)         // 0.52 MB  span tables
#define WG_OFF (SP_OFF + SP_BYTES)
#define WG_BYTES ((size_t)BB*NC*2*64*64*2)         // 134.2 MB W = bf16(P*C), [g][dir][t][dn]
#define YB_OFF (WG_OFF + WG_BYTES)
#define YB_BYTES ((size_t)BB*NC*64*4*4)            // 8.39 MB  ybase fp32 [g][t][d]

#define LOG2E 1.4426950408889634f

__device__ __forceinline__ float bf2f(unsigned short u){ return __uint_as_float(((unsigned int)u)<<16); }
__device__ __forceinline__ float blo(unsigned int u){ return __uint_as_float(u<<16); }
__device__ __forceinline__ float bhi(unsigned int u){ return __uint_as_float(u & 0xffff0000u); }

// HW packed f32->bf16 (RNE). 1 VALU inst.
__device__ __forceinline__ unsigned int cvtpk(float lo, float hi){
  unsigned int r;
  asm("v_cvt_pk_bf16_f32 %0, %1, %2" : "=v"(r) : "v"(lo), "v"(hi));
  return r;
}
__device__ __forceinline__ unsigned short cvt1(float x){
  return (unsigned short)cvtpk(x, x);
}

__device__ __forceinline__ float siluf(float x){ return x / (1.f + __expf(-x)); }
__device__ __forceinline__ float softplusf_(float x){ return fmaxf(x,0.f) + log1pf(__expf(-fabsf(x))); }

// raw v_exp_f32 (exp2). A is pre-scaled by log2(e) so no extra mul.
__device__ __forceinline__ float exp2fast(float x){
#if __has_builtin(__builtin_amdgcn_exp2f)
  return __builtin_amdgcn_exp2f(x);
#else
  float r; asm("v_exp_f32 %0, %1\ns_nop 0" : "=v"(r) : "v"(x)); return r;
#endif
}

// sum over the 16-lane DPP row (lanes n=0..15 of each d-group).
__device__ __forceinline__ float rowsum16(float x){
  asm("s_nop 1\n\t"
      "v_add_f32_dpp %0, %0, %0 row_ror:1 row_mask:0xf bank_mask:0xf\n\t"
      "s_nop 1\n\t"
      "v_add_f32_dpp %0, %0, %0 row_ror:2 row_mask:0xf bank_mask:0xf\n\t"
      "s_nop 1\n\t"
      "v_add_f32_dpp %0, %0, %0 row_ror:4 row_mask:0xf bank_mask:0xf\n\t"
      "s_nop 1\n\t"
      "v_add_f32_dpp %0, %0, %0 row_ror:8 row_mask:0xf bank_mask:0xf"
      : "+v"(x));
  return x;
}

__device__ __forceinline__ float ldw(const void* p, int i, int isf){
  return isf ? ((const float*)p)[i] : bf2f(((const unsigned short*)p)[i]);
}
__device__ __forceinline__ float2 hid2(const void* hid, int isf, int b, int t){
  if (isf){
    const float* p = (const float*)hid;
    return make_float2(p[(size_t)b*2*LL + t], p[(size_t)b*2*LL + LL + t]);
  }
  const unsigned short* p = (const unsigned short*)hid;
  return make_float2(bf2f(p[(size_t)b*2*LL + t]), bf2f(p[(size_t)b*2*LL + LL + t]));
}
__device__ __forceinline__ float4 xrow(const void* __restrict__ hid, int isf,
                                       const float* __restrict__ W, int b, int t){
  float2 h = hid2(hid, isf, b, t);
  float ms = rsqrtf(0.5f*(h.x*h.x + h.y*h.y) + 1e-5f);
  float v0 = h.x*ms*W[G_NORMW], v1 = h.y*ms*W[G_NORMW+1];
  float4 x;
  x.x = W[G_INPROJ+0]*v0 + W[G_INPROJ+1]*v1;
  x.y = W[G_INPROJ+2]*v0 + W[G_INPROJ+3]*v1;
  x.z = W[G_INPROJ+4]*v0 + W[G_INPROJ+5]*v1;
  x.w = W[G_INPROJ+6]*v0 + W[G_INPROJ+7]*v1;
  return x;
}

// ---------------- kernel 0: weight prep ----------------
__global__ void k_prep(const void* __restrict__ normw, const void* __restrict__ inpj,
    const void* __restrict__ cwf, const void* __restrict__ cbf,
    const void* __restrict__ xpf, const void* __restrict__ dwf,
    const void* __restrict__ dbf, const void* __restrict__ alf,
    const void* __restrict__ ddf,
    const void* __restrict__ cwb, const void* __restrict__ cbb,
    const void* __restrict__ xpb, const void* __restrict__ dwb,
    const void* __restrict__ dbb, const void* __restrict__ alb,
    const void* __restrict__ ddb,
    const void* __restrict__ outp, const void* __restrict__ nfw,
    float* __restrict__ W)
{
  const int isf = (((const unsigned int*)ddf)[0] == 0x3F800000u) ? 1 : 0;
  int t = threadIdx.x;
  for (int i=t;i<132;i+=256){ W[XPW+i]=ldw(xpf,i,isf); W[WD_SZ+XPW+i]=ldw(xpb,i,isf); }
  for (int i=t;i<16;i+=256){ W[CVW+i]=ldw(cwf,i,isf); W[WD_SZ+CVW+i]=ldw(cwb,i,isf); W[G_INPROJ+i]=ldw(inpj,i,isf); }
  for (int i=t;i<4;i+=256){
    W[CVB+i]=ldw(cbf,i,isf); W[WD_SZ+CVB+i]=ldw(cbb,i,isf);
    W[DTW+i]=ldw(dwf,i,isf); W[WD_SZ+DTW+i]=ldw(dwb,i,isf);
    W[DTB+i]=ldw(dbf,i,isf); W[WD_SZ+DTB+i]=ldw(dbb,i,isf);
    W[DW+i] =ldw(ddf,i,isf); W[WD_SZ+DW+i] =ldw(ddb,i,isf);
  }
  for (int i=t;i<64;i+=256){
    W[AW+i]       = -__expf(ldw(alf,i,isf)) * LOG2E;
    W[WD_SZ+AW+i] = -__expf(ldw(alb,i,isf)) * LOG2E;
  }
  for (int i=t;i<8;i+=256) W[G_OUTP+i]=ldw(outp,i,isf);
  for (int i=t;i<2;i+=256){ W[G_NORMW+i]=ldw(normw,i,isf); W[G_NORMF+i]=ldw(nfw,i,isf); }
  if (t==0) W[FLG] = (float)isf;
}

// ---- per-direction local scan: produces (P,Q), y_loc rowsums, and W=bf16(P*C).
template<int DR>
__device__ __forceinline__ float2 scan_store(const float (* __restrict__ dtPd)[68],
    const unsigned short (* __restrict__ dtud)[68],
    const unsigned int (* __restrict__ bcd)[68],
    float (* __restrict__ ySd)[68],
    unsigned short* __restrict__ wrow,   // global: [t][dn], this dir's base
    float Ax, int d, int n, int dn)
{
  unsigned short* wr   = wrow + dn;          // one-time lane offset
  unsigned short* wrHi = wr + 32*64;         // split base so imm offset < 4096B
  float P = 1.f, h = 0.f;
  for (int j4=0; j4<16; j4++){
    const int t0 = DR ? 60-4*j4 : 4*j4;
    float4  d4 = *(const float4*)&dtPd[d][t0];
    ushort4 u4 = *(const ushort4*)&dtud[d][t0];
    uint4   c4 = *(const uint4*)&bcd[n][t0];
    float da[4]={d4.x,d4.y,d4.z,d4.w};
    unsigned short ua[4]={u4.x,u4.y,u4.z,u4.w};
    unsigned int ca[4]={c4.x,c4.y,c4.z,c4.w};
    float s[4];
    #pragma unroll
    for (int jr=0; jr<4; jr++){
      const int k  = DR ? 3-jr : jr;         // bwd consumes t descending
      const int tt = t0 + k;
      float e = exp2fast(Ax*da[k]);
      P *= e;
      float Cf = bhi(ca[k]);
      h = fmaf(e, h, bf2f(ua[k])*blo(ca[k]));
      ((tt < 32) ? wr : wrHi)[(tt & 31)*64] = cvt1(P*Cf);  // coalesced 128B/t
      s[k] = rowsum16(h*Cf);
    }
    if (n == 0) *(float4*)&ySd[d][t0] = make_float4(s[0],s[1],s[2],s[3]);
  }
  return make_float2(P, h);
}

// ---------------- kernel 1: per-chunk local scan, dir per wave ----------------
__global__ __launch_bounds__(128, 4) void k_chunk2(const void* __restrict__ hid,
    const float* __restrict__ W, float2* __restrict__ PQ,
    unsigned short* __restrict__ Wg, float4* __restrict__ YB)
{
  // xb (1120B, dead after preamble) overlaps yS (2176B, written during scan)
  __shared__ __align__(16) char smx[2176];
  __shared__ __align__(16) float dtP[2][4][68];            // 2176
  __shared__ __align__(16) unsigned short dtuP[2][4][68];  // 1088
  __shared__ __align__(16) unsigned int BCp[2][16][68];    // 8704 (B | C<<16) bf16
  __shared__ __align__(16) float uD[2][256];               // 2048 u*D
  float4* xb = (float4*)smx;
  float (*yS)[4][68] = (float (*)[4][68])smx;

  const int tid  = threadIdx.x;
  const int wid  = tid >> 6;         // 0=fwd wave, 1=bwd wave
  const int lane = tid & 63;
  const int gid  = blockIdx.x;       // (b,c)
  const int c    = gid & (NC-1);
  const int b    = gid >> 9;
  const int isf  = (int)W[FLG];

  if (wid == 0){
    int t = c*64 + lane;
    xb[lane+3] = xrow(hid, isf, W, b, t);
    if (lane < 3){
      int t2 = c*64 - 3 + lane;
      float4 v = make_float4(0.f,0.f,0.f,0.f);
      if (t2 >= 0) v = xrow(hid, isf, W, b, t2);
      xb[lane] = v;
    }
    if (lane >= 61){
      int t3 = c*64 + lane + 3;
      float4 v = make_float4(0.f,0.f,0.f,0.f);
      if (t3 < LL) v = xrow(hid, isf, W, b, t3);
      xb[lane+6] = v;
    }
  }
  __syncthreads();
  {
    const float* Wd = W + wid*WD_SZ;
    float4 a0,a1,a2,a3;
    if (wid == 0){ a0=xb[lane];   a1=xb[lane+1]; a2=xb[lane+2]; a3=xb[lane+3]; }
    else         { a0=xb[lane+6]; a1=xb[lane+5]; a2=xb[lane+4]; a3=xb[lane+3]; }
    float u[4];
    u[0] = siluf(Wd[CVB+0] + Wd[CVW+ 0]*a0.x + Wd[CVW+ 1]*a1.x + Wd[CVW+ 2]*a2.x + Wd[CVW+ 3]*a3.x);
    u[1] = siluf(Wd[CVB+1] + Wd[CVW+ 4]*a0.y + Wd[CVW+ 5]*a1.y + Wd[CVW+ 6]*a2.y + Wd[CVW+ 7]*a3.y);
    u[2] = siluf(Wd[CVB+2] + Wd[CVW+ 8]*a0.z + Wd[CVW+ 9]*a1.z + Wd[CVW+10]*a2.z + Wd[CVW+11]*a3.z);
    u[3] = siluf(Wd[CVB+3] + Wd[CVW+12]*a0.w + Wd[CVW+13]*a1.w + Wd[CVW+14]*a2.w + Wd[CVW+15]*a3.w);
    float dtr = Wd[XPW+0]*u[0] + Wd[XPW+1]*u[1] + Wd[XPW+2]*u[2] + Wd[XPW+3]*u[3];
    float4 ud4;
    #pragma unroll
    for (int d2=0; d2<4; d2++){
      float dt = softplusf_(fmaf(Wd[DTW+d2], dtr, Wd[DTB+d2]));
      dtP[wid][d2][lane]  = dt;
      dtuP[wid][d2][lane] = cvt1(dt*u[d2]);
      ((float*)&ud4)[d2] = u[d2]*Wd[DW+d2];
    }
    *(float4*)&uD[wid][lane*4] = ud4;
    #pragma unroll
    for (int n=0; n<16; n++){
      float Bn = Wd[XPW+(1+n)*4+0]*u[0] + Wd[XPW+(1+n)*4+1]*u[1]
               + Wd[XPW+(1+n)*4+2]*u[2] + Wd[XPW+(1+n)*4+3]*u[3];
      float Cn = Wd[XPW+(17+n)*4+0]*u[0] + Wd[XPW+(17+n)*4+1]*u[1]
               + Wd[XPW+(17+n)*4+2]*u[2] + Wd[XPW+(17+n)*4+3]*u[3];
      BCp[wid][n][lane] = cvtpk(Bn, Cn);
    }
  }
  __syncthreads();   // also protects xb->yS union

  const int d = lane>>4, n = lane&15;
  const float Ax = W[wid*WD_SZ + AW + d*16 + n];
  unsigned short* wrow = Wg + ((size_t)gid*2 + wid)*64*64;
  float2 pq;
  size_t idx;
  if (wid == 0){
    pq  = scan_store<0>(dtP[0], dtuP[0], BCp[0], yS[0], wrow, Ax, d, n, lane);
    idx = ((size_t)(b*2+0)*NC + c);
  } else {
    pq  = scan_store<1>(dtP[1], dtuP[1], BCp[1], yS[1], wrow, Ax, d, n, lane);
    idx = ((size_t)(b*2+1)*NC + (NC-1-c));
  }
  PQ[idx*64 + lane] = pq;
  __syncthreads();

  // ybase = y_loc_f + y_loc_b + uD_f + uD_b   (fp32, [t][d] float4)
  if (wid == 0){
    float4 v;
    v.x = yS[0][0][lane] + yS[1][0][lane] + uD[0][lane*4+0] + uD[1][lane*4+0];
    v.y = yS[0][1][lane] + yS[1][1][lane] + uD[0][lane*4+1] + uD[1][lane*4+1];
    v.z = yS[0][2][lane] + yS[1][2][lane] + uD[0][lane*4+2] + uD[1][lane*4+2];
    v.w = yS[0][3][lane] + yS[1][3][lane] + uD[0][lane*4+3] + uD[1][lane*4+3];
    YB[(size_t)gid*64 + lane] = v;
  }
}

// ---------------- kernel 2: span tables (16-chunk composition) ----------------
__global__ __launch_bounds__(64) void k_spans(const float2* __restrict__ PQ,
                                              float2* __restrict__ SP)
{
  const int blk  = blockIdx.x;           // bd*NSPAN + span
  const int lane = threadIdx.x;
  const int bd   = blk >> 5, span = blk & (NSPAN-1);
  const float2* p = PQ + ((size_t)bd*NC + span*SPLEN)*64 + lane;
  float2 v[SPLEN];
  #pragma unroll
  for (int k=0;k<SPLEN;k++) v[k] = p[k*64];
  float A = 1.f, Bc = 0.f;
  #pragma unroll
  for (int k=0;k<SPLEN;k++){ A *= v[k].x; Bc = fmaf(v[k].x, Bc, v[k].y); }
  SP[((size_t)bd*NSPAN + span)*64 + lane] = make_float2(A,Bc);
}

// 16-term bf16 dot against wave-uniform h0 slice (LDS broadcast reads)
__device__ __forceinline__ float dot16(uint4 q0, uint4 q1, const float* h){
  float4 h0 = *(const float4*)(h+0),  h1 = *(const float4*)(h+4);
  float4 h2 = *(const float4*)(h+8),  h3 = *(const float4*)(h+12);
  float cacc = 0.f;
  cacc = fmaf(blo(q0.x), h0.x, cacc); cacc = fmaf(bhi(q0.x), h0.y, cacc);
  cacc = fmaf(blo(q0.y), h0.z, cacc); cacc = fmaf(bhi(q0.y), h0.w, cacc);
  cacc = fmaf(blo(q0.z), h1.x, cacc); cacc = fmaf(bhi(q0.z), h1.y, cacc);
  cacc = fmaf(blo(q0.w), h1.z, cacc); cacc = fmaf(bhi(q0.w), h1.w, cacc);
  cacc = fmaf(blo(q1.x), h2.x, cacc); cacc = fmaf(bhi(q1.x), h2.y, cacc);
  cacc = fmaf(blo(q1.y), h2.z, cacc); cacc = fmaf(bhi(q1.y), h2.w, cacc);
  cacc = fmaf(blo(q1.z), h3.x, cacc); cacc = fmaf(bhi(q1.z), h3.y, cacc);
  cacc = fmaf(blo(q1.w), h3.z, cacc); cacc = fmaf(bhi(q1.w), h3.w, cacc);
  return cacc;
}

// ---------------- kernel 3: compose h0 + apply W·h0 + combine + out ----------------
// 128 threads: wave = dir. W tile staged coalesced -> padded LDS rows,
// then per-t ds_read_b128 (row stride 144B, 16B-aligned, bank-floor).
#define WROW 72   // shorts per padded LDS row (64 data + 8 pad)
__global__ __launch_bounds__(128, 3) void k_final(const void* __restrict__ hid,
    const float* __restrict__ W, const float2* __restrict__ PQ,
    const float2* __restrict__ SP, const unsigned short* __restrict__ Wg,
    const float4* __restrict__ YB, void* __restrict__ out)
{
  __shared__ float h0s[2][64];
  __shared__ __align__(16) float yC[2][64][4];
  __shared__ __align__(16) unsigned short Wt[2][64][WROW];   // 18432 B
  const int tid  = threadIdx.x;
  const int wid  = tid >> 6;         // 0=fwd, 1=bwd
  const int lane = tid & 63;
  const int gid  = blockIdx.x;       // (b,c)
  const int c    = gid & (NC-1);
  const int b    = gid >> 9;
  const int isf  = (int)W[FLG];

  // ---- stage this dir's 8KB W tile: 8 coalesced dwordx4 loads (LLC-hot)
  const uint4* gsrc = (const uint4*)(Wg + ((size_t)gid*2 + wid)*64*64);
  uint4 st[8];
  #pragma unroll
  for (int i=0;i<8;i++) st[i] = gsrc[i*64 + lane];

  // ---- compose this dir's entry state h0 (lane = dn), hides the loads above
  {
    const int p  = wid ? (NC-1-c) : c;      // position in this dir's sequence
    const int bd = b*2 + wid;
    const int s  = p >> 4, wn = p & 15;
    const float2* SPb = SP + (size_t)bd*NSPAN*64 + lane;
    const float2* PQb = PQ + ((size_t)bd*NC + (p & ~15))*64 + lane;
    float h = 0.f;
    #pragma unroll
    for (int jg=0; jg<4; jg++){
      if (jg*8 < s){                         // wave-uniform group skip
        float2 v[8];
        #pragma unroll
        for (int j=0;j<8;j++){ int jj = jg*8+j; v[j] = SPb[(size_t)(jj<s?jj:0)*64]; }
        #pragma unroll
        for (int j=0;j<8;j++){ int jj = jg*8+j; if (jj<s) h = fmaf(v[j].x, h, v[j].y); }
      }
    }
    #pragma unroll
    for (int jg=0; jg<2; jg++){
      if (jg*8 < wn){
        float2 v[8];
        #pragma unroll
        for (int j=0;j<8;j++){ int jj = jg*8+j; v[j] = PQb[(size_t)(jj<wn?jj:0)*64]; }
        #pragma unroll
        for (int j=0;j<8;j++){ int jj = jg*8+j; if (jj<wn) h = fmaf(v[j].x, h, v[j].y); }
      }
    }
    h0s[wid][lane] = h;
  }

  // ---- scatter staged tile into padded LDS rows (16B-aligned ds_write_b128)
  #pragma unroll
  for (int i=0;i<8;i++){
    int j = i*64 + lane;                  // uint4 index: row = j>>3, quad = j&7
    *(uint4*)&Wt[wid][j>>3][(j&7)*8] = st[i];
  }
  __syncthreads();

  // ---- per-t dot (lane = t), this dir: 8 x ds_read_b128 + 4 x dot16
  {
    uint4 wr_[8];
    #pragma unroll
    for (int q=0;q<8;q++) wr_[q] = *(const uint4*)&Wt[wid][lane][q*8];
    float4 cr;
    #pragma unroll
    for (int d2=0; d2<4; d2++)
      ((float*)&cr)[d2] = dot16(wr_[d2*2], wr_[d2*2+1], &h0s[wid][d2*16]);
    *(float4*)&yC[wid][lane][0] = cr;
  }
  __syncthreads();

  // ---- epilogue (lane = t): combine + out_proj + residual + final rmsnorm.
  // Both waves compute (identical math); wave0 stores ch0, wave1 ch1.
  {
    const int t  = lane;
    const int tg = c*64 + t;
    float4 cF = *(const float4*)&yC[0][t][0];
    float4 cB = *(const float4*)&yC[1][t][0];
    float4 yb = YB[(size_t)gid*64 + t];

    float2 r = hid2(hid, isf, b, tg);
    float ms0 = rsqrtf(0.5f*(r.x*r.x + r.y*r.y) + 1e-5f);
    float v0 = r.x*ms0*W[G_NORMW], v1 = r.y*ms0*W[G_NORMW+1];
    float z0 = siluf(W[G_INPROJ+ 8]*v0 + W[G_INPROJ+ 9]*v1);
    float z1 = siluf(W[G_INPROJ+10]*v0 + W[G_INPROJ+11]*v1);
    float z2 = siluf(W[G_INPROJ+12]*v0 + W[G_INPROJ+13]*v1);
    float z3 = siluf(W[G_INPROJ+14]*v0 + W[G_INPROJ+15]*v1);

    float y0 = (yb.x + cF.x + cB.x) * z0;
    float y1 = (yb.y + cF.y + cB.y) * z1;
    float y2 = (yb.z + cF.z + cB.z) * z2;
    float y3 = (yb.w + cF.w + cB.w) * z3;
    float o0 = W[G_OUTP+0]*y0 + W[G_OUTP+1]*y1 + W[G_OUTP+2]*y2 + W[G_OUTP+3]*y3;
    float o1 = W[G_OUTP+4]*y0 + W[G_OUTP+5]*y1 + W[G_OUTP+6]*y2 + W[G_OUTP+7]*y3;
    o0 += r.x;
    o1 += r.y;
    float ms = rsqrtf(0.5f*(o0*o0 + o1*o1) + 1e-5f);
    float e0 = o0*ms*W[G_NORMF], e1 = o1*ms*W[G_NORMF+1];
    size_t i0 = (size_t)b*2*LL + tg, i1 = i0 + LL;
    if (isf){
      if (wid == 0) ((float*)out)[i0] = e0;
      else          ((float*)out)[i1] = e1;
    } else {
      if (wid == 0) ((unsigned short*)out)[i0] = cvt1(e0);
      else          ((unsigned short*)out)[i1] = cvt1(e1);
    }
  }
}

extern "C" void kernel_launch(void* const* d_in, const int* in_sizes, int n_in,
                              void* d_out, int out_size, void* d_ws, size_t ws_size,
                              hipStream_t stream)
{
  (void)in_sizes; (void)n_in; (void)out_size; (void)ws_size;
  const void* hid   = d_in[0];
  const void* normw = d_in[1];
  const void* inpj  = d_in[2];
  const void* cwf   = d_in[3];
  const void* cbf   = d_in[4];
  const void* xpf   = d_in[5];
  const void* dwf   = d_in[6];
  const void* dbf   = d_in[7];
  const void* alf   = d_in[8];
  const void* ddf   = d_in[9];
  const void* cwb   = d_in[10];
  const void* cbb   = d_in[11];
  const void* xpb   = d_in[12];
  const void* dwb   = d_in[13];
  const void* dbb   = d_in[14];
  const void* alb   = d_in[15];
  const void* ddb   = d_in[16];
  const void* outp  = d_in[17];
  const void* nfw   = d_in[18];

  float* W            = (float*)d_ws;
  float2* PQ          = (float2*)((char*)d_ws + PQ_OFF);
  float2* SPt         = (float2*)((char*)d_ws + SP_OFF);
  unsigned short* Wg  = (unsigned short*)((char*)d_ws + WG_OFF);
  float4* YB          = (float4*)((char*)d_ws + YB_OFF);

  k_prep<<<1,256,0,stream>>>(normw, inpj, cwf, cbf, xpf, dwf, dbf, alf, ddf,
                             cwb, cbb, xpb, dwb, dbb, alb, ddb, outp, nfw, W);
  k_chunk2<<<BB*NC, 128, 0, stream>>>(hid, W, PQ, Wg, YB);
  k_spans<<<BB*2*NSPAN, 64, 0, stream>>>(PQ, SPt);
  k_final<<<BB*NC, 128, 0, stream>>>(hid, W, PQ, SPt, Wg, YB, d_out);
}

// Round 5
// 181.493 us; speedup vs baseline: 1.0835x; 1.0552x over previous
//
#include <hip/hip_runtime.h>
#include <cstdint>

#define BB 16
#define LL 32768
#define NC 512               // chunks per (b,dir)
#define NSPAN 32             // NC/16 spans per (b,dir)
#define SPLEN 16             // chunks per span
#define CPG 8                // chunks per k_final block

// ---- weight block layout (floats) in ws[0..4096B) ----
#define WD_SZ 256            // per-direction block
#define XPW 0                // x_proj rows [33][4]
#define CVW 132              // conv_w [4][4]
#define CVB 148              // conv_b [4]
#define DTW 152              // dt_proj_w [4]
#define DTB 156              // dt_proj_b [4]
#define AW  160              // A = -exp(A_log)*log2(e) [4][16]  (pre-scaled for exp2)
#define DW  224              // D [4]
#define G_INPROJ 512         // in_proj [8][2]
#define G_NORMW 528
#define G_OUTP 530           // out_proj [2][4]
#define G_NORMF 538
#define FLG 1000             // 1.0f if inputs/outputs fp32, 0.0f if bf16

// ---- ws byte offsets (~152 MiB) ----
#define PQ_OFF 4096
#define PQ_BYTES ((size_t)BB*2*NC*64*8)            // 8.39 MB  per-chunk (P,Q)
#define SP_OFF (PQ_OFF + PQ_BYTES)
#define SP_BYTES ((size_t)BB*2*NSPAN*64*8)         // 0.52 MB  span tables
#define WG_OFF (SP_OFF + SP_BYTES)
#define WG_BYTES ((size_t)BB*NC*2*64*64*2)         // 134.2 MB W = bf16(P*C), [g][dir][t][dn]
#define YB_OFF (WG_OFF + WG_BYTES)
#define YB_BYTES ((size_t)BB*NC*64*4*4)            // 8.39 MB  ybase fp32 [g][t][d]

#define LOG2E 1.4426950408889634f

__device__ __forceinline__ float bf2f(unsigned short u){ return __uint_as_float(((unsigned int)u)<<16); }
__device__ __forceinline__ float blo(unsigned int u){ return __uint_as_float(u<<16); }
__device__ __forceinline__ float bhi(unsigned int u){ return __uint_as_float(u & 0xffff0000u); }

// HW packed f32->bf16 (RNE). 1 VALU inst.
__device__ __forceinline__ unsigned int cvtpk(float lo, float hi){
  unsigned int r;
  asm("v_cvt_pk_bf16_f32 %0, %1, %2" : "=v"(r) : "v"(lo), "v"(hi));
  return r;
}
__device__ __forceinline__ unsigned short cvt1(float x){
  return (unsigned short)cvtpk(x, x);
}

__device__ __forceinline__ float siluf(float x){ return x / (1.f + __expf(-x)); }
__device__ __forceinline__ float softplusf_(float x){ return fmaxf(x,0.f) + log1pf(__expf(-fabsf(x))); }

// raw v_exp_f32 (exp2). A is pre-scaled by log2(e) so no extra mul.
__device__ __forceinline__ float exp2fast(float x){
#if __has_builtin(__builtin_amdgcn_exp2f)
  return __builtin_amdgcn_exp2f(x);
#else
  float r; asm("v_exp_f32 %0, %1\ns_nop 0" : "=v"(r) : "v"(x)); return r;
#endif
}

// sum over the 16-lane DPP row (lanes n=0..15 of each d-group).
__device__ __forceinline__ float rowsum16(float x){
  asm("s_nop 1\n\t"
      "v_add_f32_dpp %0, %0, %0 row_ror:1 row_mask:0xf bank_mask:0xf\n\t"
      "s_nop 1\n\t"
      "v_add_f32_dpp %0, %0, %0 row_ror:2 row_mask:0xf bank_mask:0xf\n\t"
      "s_nop 1\n\t"
      "v_add_f32_dpp %0, %0, %0 row_ror:4 row_mask:0xf bank_mask:0xf\n\t"
      "s_nop 1\n\t"
      "v_add_f32_dpp %0, %0, %0 row_ror:8 row_mask:0xf bank_mask:0xf"
      : "+v"(x));
  return x;
}

__device__ __forceinline__ float ldw(const void* p, int i, int isf){
  return isf ? ((const float*)p)[i] : bf2f(((const unsigned short*)p)[i]);
}
__device__ __forceinline__ float2 hid2(const void* hid, int isf, int b, int t){
  if (isf){
    const float* p = (const float*)hid;
    return make_float2(p[(size_t)b*2*LL + t], p[(size_t)b*2*LL + LL + t]);
  }
  const unsigned short* p = (const unsigned short*)hid;
  return make_float2(bf2f(p[(size_t)b*2*LL + t]), bf2f(p[(size_t)b*2*LL + LL + t]));
}
__device__ __forceinline__ float4 xrow(const void* __restrict__ hid, int isf,
                                       const float* __restrict__ W, int b, int t){
  float2 h = hid2(hid, isf, b, t);
  float ms = rsqrtf(0.5f*(h.x*h.x + h.y*h.y) + 1e-5f);
  float v0 = h.x*ms*W[G_NORMW], v1 = h.y*ms*W[G_NORMW+1];
  float4 x;
  x.x = W[G_INPROJ+0]*v0 + W[G_INPROJ+1]*v1;
  x.y = W[G_INPROJ+2]*v0 + W[G_INPROJ+3]*v1;
  x.z = W[G_INPROJ+4]*v0 + W[G_INPROJ+5]*v1;
  x.w = W[G_INPROJ+6]*v0 + W[G_INPROJ+7]*v1;
  return x;
}

// ---------------- kernel 0: weight prep ----------------
__global__ void k_prep(const void* __restrict__ normw, const void* __restrict__ inpj,
    const void* __restrict__ cwf, const void* __restrict__ cbf,
    const void* __restrict__ xpf, const void* __restrict__ dwf,
    const void* __restrict__ dbf, const void* __restrict__ alf,
    const void* __restrict__ ddf,
    const void* __restrict__ cwb, const void* __restrict__ cbb,
    const void* __restrict__ xpb, const void* __restrict__ dwb,
    const void* __restrict__ dbb, const void* __restrict__ alb,
    const void* __restrict__ ddb,
    const void* __restrict__ outp, const void* __restrict__ nfw,
    float* __restrict__ W)
{
  const int isf = (((const unsigned int*)ddf)[0] == 0x3F800000u) ? 1 : 0;
  int t = threadIdx.x;
  for (int i=t;i<132;i+=256){ W[XPW+i]=ldw(xpf,i,isf); W[WD_SZ+XPW+i]=ldw(xpb,i,isf); }
  for (int i=t;i<16;i+=256){ W[CVW+i]=ldw(cwf,i,isf); W[WD_SZ+CVW+i]=ldw(cwb,i,isf); W[G_INPROJ+i]=ldw(inpj,i,isf); }
  for (int i=t;i<4;i+=256){
    W[CVB+i]=ldw(cbf,i,isf); W[WD_SZ+CVB+i]=ldw(cbb,i,isf);
    W[DTW+i]=ldw(dwf,i,isf); W[WD_SZ+DTW+i]=ldw(dwb,i,isf);
    W[DTB+i]=ldw(dbf,i,isf); W[WD_SZ+DTB+i]=ldw(dbb,i,isf);
    W[DW+i] =ldw(ddf,i,isf); W[WD_SZ+DW+i] =ldw(ddb,i,isf);
  }
  for (int i=t;i<64;i+=256){
    W[AW+i]       = -__expf(ldw(alf,i,isf)) * LOG2E;
    W[WD_SZ+AW+i] = -__expf(ldw(alb,i,isf)) * LOG2E;
  }
  for (int i=t;i<8;i+=256) W[G_OUTP+i]=ldw(outp,i,isf);
  for (int i=t;i<2;i+=256){ W[G_NORMW+i]=ldw(normw,i,isf); W[G_NORMF+i]=ldw(nfw,i,isf); }
  if (t==0) W[FLG] = (float)isf;
}

// ---- per-direction local scan: produces (P,Q), y_loc rowsums, and W=bf16(P*C).
template<int DR>
__device__ __forceinline__ float2 scan_store(const float (* __restrict__ dtPd)[68],
    const unsigned short (* __restrict__ dtud)[68],
    const unsigned int (* __restrict__ bcd)[68],
    float (* __restrict__ ySd)[68],
    unsigned short* __restrict__ wrow,   // global: [t][dn], this dir's base
    float Ax, int d, int n, int dn)
{
  unsigned short* wr   = wrow + dn;          // one-time lane offset
  unsigned short* wrHi = wr + 32*64;         // split base so imm offset < 4096B
  float P = 1.f, h = 0.f;
  for (int j4=0; j4<16; j4++){
    const int t0 = DR ? 60-4*j4 : 4*j4;
    float4  d4 = *(const float4*)&dtPd[d][t0];
    ushort4 u4 = *(const ushort4*)&dtud[d][t0];
    uint4   c4 = *(const uint4*)&bcd[n][t0];
    float da[4]={d4.x,d4.y,d4.z,d4.w};
    unsigned short ua[4]={u4.x,u4.y,u4.z,u4.w};
    unsigned int ca[4]={c4.x,c4.y,c4.z,c4.w};
    float s[4];
    #pragma unroll
    for (int jr=0; jr<4; jr++){
      const int k  = DR ? 3-jr : jr;         // bwd consumes t descending
      const int tt = t0 + k;
      float e = exp2fast(Ax*da[k]);
      P *= e;
      float Cf = bhi(ca[k]);
      h = fmaf(e, h, bf2f(ua[k])*blo(ca[k]));
      ((tt < 32) ? wr : wrHi)[(tt & 31)*64] = cvt1(P*Cf);  // coalesced 128B/t
      s[k] = rowsum16(h*Cf);
    }
    if (n == 0) *(float4*)&ySd[d][t0] = make_float4(s[0],s[1],s[2],s[3]);
  }
  return make_float2(P, h);
}

// ---------------- kernel 1: per-chunk local scan, dir per wave ----------------
__global__ __launch_bounds__(128, 4) void k_chunk2(const void* __restrict__ hid,
    const float* __restrict__ W, float2* __restrict__ PQ,
    unsigned short* __restrict__ Wg, float4* __restrict__ YB)
{
  // xb (1120B, dead after preamble) overlaps yS (2176B, written during scan)
  __shared__ __align__(16) char smx[2176];
  __shared__ __align__(16) float dtP[2][4][68];            // 2176
  __shared__ __align__(16) unsigned short dtuP[2][4][68];  // 1088
  __shared__ __align__(16) unsigned int BCp[2][16][68];    // 8704 (B | C<<16) bf16
  __shared__ __align__(16) float uD[2][256];               // 2048 u*D
  float4* xb = (float4*)smx;
  float (*yS)[4][68] = (float (*)[4][68])smx;

  const int tid  = threadIdx.x;
  const int wid  = tid >> 6;         // 0=fwd wave, 1=bwd wave
  const int lane = tid & 63;
  const int gid  = blockIdx.x;       // (b,c)
  const int c    = gid & (NC-1);
  const int b    = gid >> 9;
  const int isf  = (int)W[FLG];

  if (wid == 0){
    int t = c*64 + lane;
    xb[lane+3] = xrow(hid, isf, W, b, t);
    if (lane < 3){
      int t2 = c*64 - 3 + lane;
      float4 v = make_float4(0.f,0.f,0.f,0.f);
      if (t2 >= 0) v = xrow(hid, isf, W, b, t2);
      xb[lane] = v;
    }
    if (lane >= 61){
      int t3 = c*64 + lane + 3;
      float4 v = make_float4(0.f,0.f,0.f,0.f);
      if (t3 < LL) v = xrow(hid, isf, W, b, t3);
      xb[lane+6] = v;
    }
  }
  __syncthreads();
  {
    const float* Wd = W + wid*WD_SZ;
    float4 a0,a1,a2,a3;
    if (wid == 0){ a0=xb[lane];   a1=xb[lane+1]; a2=xb[lane+2]; a3=xb[lane+3]; }
    else         { a0=xb[lane+6]; a1=xb[lane+5]; a2=xb[lane+4]; a3=xb[lane+3]; }
    float u[4];
    u[0] = siluf(Wd[CVB+0] + Wd[CVW+ 0]*a0.x + Wd[CVW+ 1]*a1.x + Wd[CVW+ 2]*a2.x + Wd[CVW+ 3]*a3.x);
    u[1] = siluf(Wd[CVB+1] + Wd[CVW+ 4]*a0.y + Wd[CVW+ 5]*a1.y + Wd[CVW+ 6]*a2.y + Wd[CVW+ 7]*a3.y);
    u[2] = siluf(Wd[CVB+2] + Wd[CVW+ 8]*a0.z + Wd[CVW+ 9]*a1.z + Wd[CVW+10]*a2.z + Wd[CVW+11]*a3.z);
    u[3] = siluf(Wd[CVB+3] + Wd[CVW+12]*a0.w + Wd[CVW+13]*a1.w + Wd[CVW+14]*a2.w + Wd[CVW+15]*a3.w);
    float dtr = Wd[XPW+0]*u[0] + Wd[XPW+1]*u[1] + Wd[XPW+2]*u[2] + Wd[XPW+3]*u[3];
    float4 ud4;
    #pragma unroll
    for (int d2=0; d2<4; d2++){
      float dt = softplusf_(fmaf(Wd[DTW+d2], dtr, Wd[DTB+d2]));
      dtP[wid][d2][lane]  = dt;
      dtuP[wid][d2][lane] = cvt1(dt*u[d2]);
      ((float*)&ud4)[d2] = u[d2]*Wd[DW+d2];
    }
    *(float4*)&uD[wid][lane*4] = ud4;
    #pragma unroll
    for (int n=0; n<16; n++){
      float Bn = Wd[XPW+(1+n)*4+0]*u[0] + Wd[XPW+(1+n)*4+1]*u[1]
               + Wd[XPW+(1+n)*4+2]*u[2] + Wd[XPW+(1+n)*4+3]*u[3];
      float Cn = Wd[XPW+(17+n)*4+0]*u[0] + Wd[XPW+(17+n)*4+1]*u[1]
               + Wd[XPW+(17+n)*4+2]*u[2] + Wd[XPW+(17+n)*4+3]*u[3];
      BCp[wid][n][lane] = cvtpk(Bn, Cn);
    }
  }
  __syncthreads();   // also protects xb->yS union

  const int d = lane>>4, n = lane&15;
  const float Ax = W[wid*WD_SZ + AW + d*16 + n];
  unsigned short* wrow = Wg + ((size_t)gid*2 + wid)*64*64;
  float2 pq;
  size_t idx;
  if (wid == 0){
    pq  = scan_store<0>(dtP[0], dtuP[0], BCp[0], yS[0], wrow, Ax, d, n, lane);
    idx = ((size_t)(b*2+0)*NC + c);
  } else {
    pq  = scan_store<1>(dtP[1], dtuP[1], BCp[1], yS[1], wrow, Ax, d, n, lane);
    idx = ((size_t)(b*2+1)*NC + (NC-1-c));
  }
  PQ[idx*64 + lane] = pq;
  __syncthreads();

  // ybase = y_loc_f + y_loc_b + uD_f + uD_b   (fp32, [t][d] float4)
  if (wid == 0){
    float4 v;
    v.x = yS[0][0][lane] + yS[1][0][lane] + uD[0][lane*4+0] + uD[1][lane*4+0];
    v.y = yS[0][1][lane] + yS[1][1][lane] + uD[0][lane*4+1] + uD[1][lane*4+1];
    v.z = yS[0][2][lane] + yS[1][2][lane] + uD[0][lane*4+2] + uD[1][lane*4+2];
    v.w = yS[0][3][lane] + yS[1][3][lane] + uD[0][lane*4+3] + uD[1][lane*4+3];
    YB[(size_t)gid*64 + lane] = v;
  }
}

// ---------------- kernel 2: span tables (16-chunk composition) ----------------
__global__ __launch_bounds__(64) void k_spans(const float2* __restrict__ PQ,
                                              float2* __restrict__ SP)
{
  const int blk  = blockIdx.x;           // bd*NSPAN + span
  const int lane = threadIdx.x;
  const int bd   = blk >> 5, span = blk & (NSPAN-1);
  const float2* p = PQ + ((size_t)bd*NC + span*SPLEN)*64 + lane;
  float2 v[SPLEN];
  #pragma unroll
  for (int k=0;k<SPLEN;k++) v[k] = p[k*64];
  float A = 1.f, Bc = 0.f;
  #pragma unroll
  for (int k=0;k<SPLEN;k++){ A *= v[k].x; Bc = fmaf(v[k].x, Bc, v[k].y); }
  SP[((size_t)bd*NSPAN + span)*64 + lane] = make_float2(A,Bc);
}

// 16-term bf16 dot against wave-uniform h0 slice (LDS broadcast reads)
__device__ __forceinline__ float dot16(uint4 q0, uint4 q1, const float* h){
  float4 h0 = *(const float4*)(h+0),  h1 = *(const float4*)(h+4);
  float4 h2 = *(const float4*)(h+8),  h3 = *(const float4*)(h+12);
  float cacc = 0.f;
  cacc = fmaf(blo(q0.x), h0.x, cacc); cacc = fmaf(bhi(q0.x), h0.y, cacc);
  cacc = fmaf(blo(q0.y), h0.z, cacc); cacc = fmaf(bhi(q0.y), h0.w, cacc);
  cacc = fmaf(blo(q0.z), h1.x, cacc); cacc = fmaf(bhi(q0.z), h1.y, cacc);
  cacc = fmaf(blo(q0.w), h1.z, cacc); cacc = fmaf(bhi(q0.w), h1.w, cacc);
  cacc = fmaf(blo(q1.x), h2.x, cacc); cacc = fmaf(bhi(q1.x), h2.y, cacc);
  cacc = fmaf(blo(q1.y), h2.z, cacc); cacc = fmaf(bhi(q1.y), h2.w, cacc);
  cacc = fmaf(blo(q1.z), h3.x, cacc); cacc = fmaf(bhi(q1.z), h3.y, cacc);
  cacc = fmaf(blo(q1.w), h3.z, cacc); cacc = fmaf(bhi(q1.w), h3.w, cacc);
  return cacc;
}

// compose entry state for (bd, position p): s full spans + wn chunk entries
__device__ __forceinline__ float compose_h0(const float2* __restrict__ PQ,
    const float2* __restrict__ SP, int bd, int p, int lane)
{
  const int s  = p >> 4, wn = p & 15;
  const float2* SPb = SP + (size_t)bd*NSPAN*64 + lane;
  const float2* PQb = PQ + ((size_t)bd*NC + (p & ~15))*64 + lane;
  float h = 0.f;
  #pragma unroll
  for (int jg=0; jg<4; jg++){
    if (jg*8 < s){                         // wave-uniform group skip
      float2 v[8];
      #pragma unroll
      for (int j=0;j<8;j++){ int jj = jg*8+j; v[j] = SPb[(size_t)(jj<s?jj:0)*64]; }
      #pragma unroll
      for (int j=0;j<8;j++){ int jj = jg*8+j; if (jj<s) h = fmaf(v[j].x, h, v[j].y); }
    }
  }
  #pragma unroll
  for (int jg=0; jg<2; jg++){
    if (jg*8 < wn){
      float2 v[8];
      #pragma unroll
      for (int j=0;j<8;j++){ int jj = jg*8+j; v[j] = PQb[(size_t)(jj<wn?jj:0)*64]; }
      #pragma unroll
      for (int j=0;j<8;j++){ int jj = jg*8+j; if (jj<wn) h = fmaf(v[j].x, h, v[j].y); }
    }
  }
  return h;
}

// ---------------- kernel 3: 8-chunk batched correction + epilogue ----------------
// 1024 blocks x 128 thr. wave = dir; wave0 walks chunks ascending, wave1
// descending (so both h0 states update incrementally, 1 fma per chunk).
// No barriers inside the loop: each wave owns its Wt/yC/h0 halves.
#define WROW 72   // shorts per padded LDS row (64 data + 8 pad)
__global__ __launch_bounds__(128, 2) void k_final(const void* __restrict__ hid,
    const float* __restrict__ W, const float2* __restrict__ PQ,
    const float2* __restrict__ SP, const unsigned short* __restrict__ Wg,
    const float4* __restrict__ YB, void* __restrict__ out)
{
  __shared__ __align__(16) unsigned short Wt[2][64][WROW];   // 18432 B
  __shared__ __align__(16) float yC[2][CPG][64][4];          // 16384 B
  __shared__ __align__(16) float h0s[2][64];                 //   512 B
  const int tid  = threadIdx.x;
  const int wid  = tid >> 6;         // 0=fwd, 1=bwd
  const int lane = tid & 63;
  const int gb   = blockIdx.x;       // b*(NC/CPG) + cg
  const int b    = gb >> 6;
  const int c0   = (gb & 63) * CPG;
  const int isf  = (int)W[FLG];
  const int bd   = b*2 + wid;

  // first chunk index for this wave's iteration order
  const int i_first = wid ? (CPG-1) : 0;
  const int c_first = c0 + i_first;
  const int p_first = wid ? (NC-1-c_first) : c_first;

  // prologue: issue first tile loads, then compose h0 (hides latency)
  const uint4* gt0 = (const uint4*)(Wg + ((size_t)(b*NC + c_first)*2 + wid)*64*64);
  uint4 st[8];
  #pragma unroll
  for (int k2=0;k2<8;k2++) st[k2] = gt0[k2*64 + lane];

  float h = compose_h0(PQ, SP, bd, p_first, lane);

  // scatter first tile
  #pragma unroll
  for (int k2=0;k2<8;k2++){
    int j = k2*64 + lane;
    *(uint4*)&Wt[wid][j>>3][(j&7)*8] = st[k2];
  }

  const float2* PQd = PQ + (size_t)bd*NC*64 + lane;   // index by position q

  for (int step=0; step<CPG; ++step){
    const int i_cur = wid ? (CPG-1-step) : step;
    const int c_cur = c0 + i_cur;
    const int hasN  = (step < CPG-1);
    const int i_nxt = wid ? (i_cur-1) : (i_cur+1);

    // issue next tile loads early
    uint4 sn[8];
    if (hasN){
      const uint4* g2 = (const uint4*)(Wg + ((size_t)(b*NC + c0 + i_nxt)*2 + wid)*64*64);
      #pragma unroll
      for (int k2=0;k2<8;k2++) sn[k2] = g2[k2*64 + lane];
    }

    // publish h0 (own half; same-wave LDS ordering via lgkmcnt)
    h0s[wid][lane] = h;

    // dot for current chunk: 8 x ds_read_b128 + 4 x dot16
    {
      uint4 wr_[8];
      #pragma unroll
      for (int q=0;q<8;q++) wr_[q] = *(const uint4*)&Wt[wid][lane][q*8];
      float4 cr;
      #pragma unroll
      for (int d2=0; d2<4; d2++)
        ((float*)&cr)[d2] = dot16(wr_[d2*2], wr_[d2*2+1], &h0s[wid][d2*16]);
      *(float4*)&yC[wid][i_cur][lane][0] = cr;
    }

    // advance h by this chunk's (P,Q)
    if (hasN){
      const int q = wid ? (NC-1-c_cur) : c_cur;
      float2 pq = PQd[(size_t)q*64];
      h = fmaf(pq.x, h, pq.y);
      // scatter next tile (after our Wt reads; same-wave order)
      #pragma unroll
      for (int k2=0;k2<8;k2++){
        int j = k2*64 + lane;
        *(uint4*)&Wt[wid][j>>3][(j&7)*8] = sn[k2];
      }
    }
  }
  __syncthreads();

  // epilogue: each wave handles CPG/2 chunks; lane = t within chunk
  #pragma unroll
  for (int ii=0; ii<CPG/2; ii++){
    const int i  = wid*(CPG/2) + ii;
    const int c  = c0 + i;
    const int t  = lane;
    const int tg = c*64 + t;
    float4 cF = *(const float4*)&yC[0][i][t][0];
    float4 cB = *(const float4*)&yC[1][i][t][0];
    float4 yb = YB[(size_t)(b*NC + c)*64 + t];

    float2 r = hid2(hid, isf, b, tg);
    float ms0 = rsqrtf(0.5f*(r.x*r.x + r.y*r.y) + 1e-5f);
    float v0 = r.x*ms0*W[G_NORMW], v1 = r.y*ms0*W[G_NORMW+1];
    float z0 = siluf(W[G_INPROJ+ 8]*v0 + W[G_INPROJ+ 9]*v1);
    float z1 = siluf(W[G_INPROJ+10]*v0 + W[G_INPROJ+11]*v1);
    float z2 = siluf(W[G_INPROJ+12]*v0 + W[G_INPROJ+13]*v1);
    float z3 = siluf(W[G_INPROJ+14]*v0 + W[G_INPROJ+15]*v1);

    float y0 = (yb.x + cF.x + cB.x) * z0;
    float y1 = (yb.y + cF.y + cB.y) * z1;
    float y2 = (yb.z + cF.z + cB.z) * z2;
    float y3 = (yb.w + cF.w + cB.w) * z3;
    float o0 = W[G_OUTP+0]*y0 + W[G_OUTP+1]*y1 + W[G_OUTP+2]*y2 + W[G_OUTP+3]*y3;
    float o1 = W[G_OUTP+4]*y0 + W[G_OUTP+5]*y1 + W[G_OUTP+6]*y2 + W[G_OUTP+7]*y3;
    o0 += r.x;
    o1 += r.y;
    float ms = rsqrtf(0.5f*(o0*o0 + o1*o1) + 1e-5f);
    float e0 = o0*ms*W[G_NORMF], e1 = o1*ms*W[G_NORMF+1];
    size_t i0 = (size_t)b*2*LL + tg, i1 = i0 + LL;
    if (isf){
      ((float*)out)[i0] = e0;
      ((float*)out)[i1] = e1;
    } else {
      ((unsigned short*)out)[i0] = cvt1(e0);
      ((unsigned short*)out)[i1] = cvt1(e1);
    }
  }
}

extern "C" void kernel_launch(void* const* d_in, const int* in_sizes, int n_in,
                              void* d_out, int out_size, void* d_ws, size_t ws_size,
                              hipStream_t stream)
{
  (void)in_sizes; (void)n_in; (void)out_size; (void)ws_size;
  const void* hid   = d_in[0];
  const void* normw = d_in[1];
  const void* inpj  = d_in[2];
  const void* cwf   = d_in[3];
  const void* cbf   = d_in[4];
  const void* xpf   = d_in[5];
  const void* dwf   = d_in[6];
  const void* dbf   = d_in[7];
  const void* alf   = d_in[8];
  const void* ddf   = d_in[9];
  const void* cwb   = d_in[10];
  const void* cbb   = d_in[11];
  const void* xpb   = d_in[12];
  const void* dwb   = d_in[13];
  const void* dbb   = d_in[14];
  const void* alb   = d_in[15];
  const void* ddb   = d_in[16];
  const void* outp  = d_in[17];
  const void* nfw   = d_in[18];

  float* W            = (float*)d_ws;
  float2* PQ          = (float2*)((char*)d_ws + PQ_OFF);
  float2* SPt         = (float2*)((char*)d_ws + SP_OFF);
  unsigned short* Wg  = (unsigned short*)((char*)d_ws + WG_OFF);
  float4* YB          = (float4*)((char*)d_ws + YB_OFF);

  k_prep<<<1,256,0,stream>>>(normw, inpj, cwf, cbf, xpf, dwf, dbf, alf, ddf,
                             cwb, cbb, xpb, dwb, dbb, alb, ddb, outp, nfw, W);
  k_chunk2<<<BB*NC, 128, 0, stream>>>(hid, W, PQ, Wg, YB);
  k_spans<<<BB*2*NSPAN, 64, 0, stream>>>(PQ, SPt);
  k_final<<<BB*(NC/CPG), 128, 0, stream>>>(hid, W, PQ, SPt, Wg, YB, d_out);
}